// Round 12
// baseline (836.193 us; speedup 1.0000x reference)
//
#include <hip/hip_runtime.h>
#include <hip/hip_bf16.h>

#define DOF 69
#define NL 6
#define NH 8
#define DMODEL 512
#define DFF 2048
#define HD 64
#define BB 8
#define TT 512
#define MTOK (BB*TT)   // 4096
#define EROWS 1040     // 2T-1 = 1023, padded
#define CATP 192       // padded concat pitch (K=138 rounded to 64)
#define QKP 1024       // fused q|k row pitch (v split out transposed)

// workspace layout (bytes) — ~75 MB total (harness ws >= 256 MB per fill traces)
#define E_OFF     4096u
#define H_OFF     (512u*1024u)
#define HN_OFF    (H_OFF + 8u*1024u*1024u)
#define QKV_OFF   (HN_OFF + 4u*1024u*1024u)      // 16 MB region: qk(8MB)+VT(4MB) / mid(16MB) / scratch
#define WT_OFF    (QKV_OFF + 16u*1024u*1024u)    // 36 MB: 6 layers of bf16 B^T weights + enc/dec tail
#define LWT_ELEMS 3145728u                       // per-layer bf16 elems (qkv|wo|f1|f2)

typedef const float* fp32p;
typedef __hip_bfloat16 bf16;
typedef const bf16* bf16p;
typedef __attribute__((ext_vector_type(8))) short bf16x8;  // 8 bf16 (4 VGPRs)
typedef __attribute__((ext_vector_type(4))) short s16x4;   // 4 bf16 (8B store)
typedef __attribute__((ext_vector_type(4))) float f32x4;   // 4 fp32 acc

typedef __attribute__((address_space(1))) const void as1_cvoid;
typedef __attribute__((address_space(3))) void       as3_void;

__device__ __forceinline__ void gload16(const bf16* g, const bf16* l){
    __builtin_amdgcn_global_load_lds((as1_cvoid*)g, (as3_void*)l, 16, 0, 0);
}

__device__ __forceinline__ float b2f(bf16 x){ return __bfloat162float(x); }

// ---------------- concat(x, mask) fp32 -> bf16, zero-padded to pitch CATP ----------------
__global__ __launch_bounds__(256)
void k_concat(fp32p x, fp32p mask, bf16* __restrict__ out){
    int idx = blockIdx.x*256 + threadIdx.x;
    if (idx >= MTOK*CATP) return;
    int row = idx / CATP, c = idx - row*CATP;
    float v = 0.f;
    if (c < DOF) v = x[(size_t)row*DOF + c];
    else if (c < 2*DOF) v = mask[(size_t)row*DOF + (c - DOF)];
    out[idx] = __float2bfloat16(v);
}

// ---------------- ALL weight transposes (6 layers + enc + dec) in ONE dispatch ----------
// 64x64 tiles: float4 reads (coalesced 1KB/wave) + short8 FULL-LINE writes (one 128B
// line per n-row) -> no partial-line write amplification.
__global__ __launch_bounds__(256)
void k_wtall(fp32p wq, fp32p wk, fp32p wv, fp32p wo, fp32p fw1, fp32p fw2,
             fp32p enc_w1, fp32p enc_w2, fp32p dec_w1, fp32p dec_w2,
             bf16* __restrict__ lwt, bf16* __restrict__ ed)
{
    __shared__ float s[64][65];
    const int t = blockIdx.x;
    const int tid = threadIdx.x;

    if (t < 4608) {
        const int l = t / 768, u = t - l*768;
        bf16* base = lwt + (size_t)l*LWT_ELEMS;
        fp32p src; bf16* dst; int N, ldk, k0, n0;
        if (u < 256) {
            int seg = u >> 6, local = u & 63;
            N = 512; ldk = 512;
            k0 = (local & 7) * 64; n0 = (local >> 3) * 64;
            size_t oW = (size_t)l*512*512;
            if      (seg == 0) { src = wq + oW; dst = base; }
            else if (seg == 1) { src = wk + oW; dst = base + 262144; }
            else if (seg == 2) { src = wv + oW; dst = base + 524288; }
            else               { src = wo + oW; dst = base + 786432; }
        } else if (u < 512) {
            int local = u - 256;
            N = 2048; ldk = 512;
            k0 = (local & 7) * 64; n0 = (local >> 3) * 64;
            src = fw1 + (size_t)l*512*2048; dst = base + 1048576;
        } else {
            int local = u - 512;
            N = 512; ldk = 2048;
            k0 = (local >> 3) * 64; n0 = (local & 7) * 64;
            src = fw2 + (size_t)l*2048*512; dst = base + 2097152;
        }
        #pragma unroll
        for (int j = 0; j < 4; ++j) {
            int idx = j*256 + tid;
            int row = idx >> 4, cq = idx & 15;
            float4 v = *(const float4*)(src + (size_t)(k0+row)*N + n0 + cq*4);
            s[row][cq*4+0] = v.x; s[row][cq*4+1] = v.y;
            s[row][cq*4+2] = v.z; s[row][cq*4+3] = v.w;
        }
        __syncthreads();
        #pragma unroll
        for (int j = 0; j < 2; ++j) {
            int idx = j*256 + tid;
            int n = idx >> 3, oct = idx & 7;
            bf16x8 pack;
            #pragma unroll
            for (int e = 0; e < 8; ++e) {
                bf16 cb = __float2bfloat16(s[oct*8 + e][n]);
                ((short*)&pack)[e] = *reinterpret_cast<short*>(&cb);
            }
            *(bf16x8*)(dst + (size_t)(n0+n)*ldk + k0 + oct*8) = pack;
        }
        return;
    }

    // guarded tail: enc/dec (few blocks, scalar path)
    int t2 = t - 4608;
    fp32p src; bf16* dst; int K, N, ldk, k0, n0;
    if (t2 < 24)       { src = enc_w1; dst = ed;          K = 2*DOF; N = 512; ldk = CATP; k0 = (t2 % 3)*64; n0 = (t2 / 3)*64; }
    else if (t2 < 88)  { int lx = t2 - 24;  src = enc_w2; dst = ed + 512*CATP;          K = 512; N = 512;   ldk = 512; k0 = (lx & 7)*64; n0 = (lx >> 3)*64; }
    else if (t2 < 152) { int lx = t2 - 88;  src = dec_w1; dst = ed + 512*CATP + 262144; K = 512; N = 512;   ldk = 512; k0 = (lx & 7)*64; n0 = (lx >> 3)*64; }
    else               { int lx = t2 - 152; src = dec_w2; dst = ed + 512*CATP + 524288; K = 512; N = DOF+4; ldk = 512; k0 = (lx >> 1)*64; n0 = (lx & 1)*64; }
    for (int idx = tid; idx < 4096; idx += 256) {
        int row = idx >> 6, c = idx & 63;
        int k = k0 + row, n = n0 + c;
        s[row][c] = (k < K && n < N) ? src[(size_t)k*N + n] : 0.f;
    }
    __syncthreads();
    for (int idx = tid; idx < 4096; idx += 256) {
        int n = idx >> 6, c = idx & 63;
        if (n0 + n < N) dst[(size_t)n0 ? (size_t)(n0+n)*ldk + k0 + c : (size_t)(n0+n)*ldk + k0 + c] = __float2bfloat16(s[c][n]);
    }
}

// ---------------- LDS-tiled MFMA GEMM (BK=64, proven __syncthreads 2-phase) ----------
// C = epi(A @ B + bias); A bf16 (M x K) lda; BT bf16 (N x ldk) = B^T.
// Block = 256 threads (4 waves, 2x2 wave grid), tile BM x BN, BK=64.
// BM=32 tiles -> 4 blocks/CU (4 waves/SIMD): latency hiding via TLP is the only
// mechanism that works at this tile size (per-slab compute ~60cy << ~400cy L2
// latency; round-8's 1->2 blocks/CU win was this same lever).
// global_load_lds (16B) stages into double-buffered linear LDS; 8-chunk XOR swizzle
// (chunk ^ row&7) on GLOBAL source and LDS READ (both-sides involution, rule #21).
// XCD-aware chunked block swizzle (T1/m204). Requires K%64==0, M%BM==0.
// BIAS: 0=none, 1=bias[], 3=segment-select of {bias,bias2,bias3} by col/512.
// OUTM: 0=bf16, 1=fp32, 2=fp32 Cout + bf16 dual-dst (VTout), 3=decoder split+sigmoid.
// SPLITV: blocks with bn>=1024 write transposed per-head VT[b][h][d][t] (QKV fusion).
template<int BM, int BN, int PRELU, int RESID, int BIAS, int OUTM, int SPLITV>
__global__ __launch_bounds__(256)
void k_gemm(bf16p A, int lda,
            bf16p BT, int ldk,
            fp32p bias, fp32p bias2, fp32p bias3, size_t biasoff,
            fp32p alpha, size_t aidx,
            const float* __restrict__ resid,
            void* __restrict__ Cout, int ldc,
            bf16* __restrict__ VTout,
            int M, int N, int K)
{
    constexpr int MF = BM/32;
    constexpr int NF = BN/32;
    constexpr int AI = BM/32;   // A stage issues per wave (8 rows x 128B each)
    constexpr int BI = BN/32;

    __shared__ __attribute__((aligned(16))) bf16 sA[2][BM*64];
    __shared__ __attribute__((aligned(16))) bf16 sB[2][BN*64];

    // XCD-aware bijective swizzle (m204)
    int bx, by;
    {
        const int gx  = gridDim.x;
        const int nwg = gx * gridDim.y;
        const int bid = blockIdx.y * gx + blockIdx.x;
        const int qq = nwg >> 3, rr = nwg & 7;
        const int xcd = bid & 7, pos = bid >> 3;
        const int nb = (xcd < rr) ? (xcd*(qq+1) + pos) : (rr*(qq+1) + (xcd-rr)*qq + pos);
        bx = nb % gx; by = nb / gx;
    }

    const int tid  = threadIdx.x;
    const int w    = tid >> 6;
    const int lane = tid & 63;
    const int qd   = lane >> 4;
    const int cl   = lane & 15;
    const int wr   = w >> 1;
    const int wc   = w & 1;
    const int bm   = by * BM;
    const int bn   = bx * BN;

    const int ssc = (lane & 7) ^ ((lane >> 3) & 7);

    const bf16* aG = A + (size_t)(bm + w*(BM/4) + (lane >> 3))*lda + ssc*8;
    const bf16* bG[BI];
    #pragma unroll
    for (int i = 0; i < BI; ++i) {
        int rrow = min(bn + w*(BN/4) + i*8 + (lane >> 3), N-1);
        bG[i] = BT + (size_t)rrow*ldk + ssc*8;
    }

    f32x4 acc[MF][NF] = {};

    auto stage = [&](int p, int k0){
        #pragma unroll
        for (int i = 0; i < AI; ++i)
            gload16(aG + (size_t)(i*8)*lda + k0, &sA[p][(w*(BM/4) + i*8)*64]);
        #pragma unroll
        for (int i = 0; i < BI; ++i)
            gload16(bG[i] + k0, &sB[p][(w*(BN/4) + i*8)*64]);
    };

    stage(0, 0);
    int p = 0;
    for (int k0 = 0; k0 < K; k0 += 64) {
        __syncthreads();                       // drains vmcnt: buf[p] ready
        if (k0 + 64 < K) stage(p^1, k0 + 64);  // issue next slab under compute
        #pragma unroll
        for (int ks = 0; ks < 2; ++ks) {
            const int rcc = ks*4 + qd;
            bf16x8 aF[MF], bF[NF];
            #pragma unroll
            for (int mt = 0; mt < MF; ++mt) {
                int row = wr*(BM/2) + mt*16 + cl;
                aF[mt] = *(const bf16x8*)(&sA[p][row*64 + ((rcc ^ (cl & 7))*8)]);
            }
            #pragma unroll
            for (int nt = 0; nt < NF; ++nt) {
                int row = wc*(BN/2) + nt*16 + cl;
                bF[nt] = *(const bf16x8*)(&sB[p][row*64 + ((rcc ^ (cl & 7))*8)]);
            }
            #pragma unroll
            for (int mt = 0; mt < MF; ++mt)
                #pragma unroll
                for (int nt = 0; nt < NF; ++nt)
                    acc[mt][nt] = __builtin_amdgcn_mfma_f32_16x16x32_bf16(aF[mt], bF[nt], acc[mt][nt], 0, 0, 0);
        }
        p ^= 1;
    }

    if (SPLITV && bn >= 1024) {
        // V segment: write transposed VT[((b*8+h)*64+hd)*512 + t], 8B short4 stores
        #pragma unroll
        for (int nt = 0; nt < NF; ++nt) {
            int col = bn + wc*(BN/2) + nt*16 + cl;
            float bv = bias3[biasoff + (col & 511)];
            int hh = (col >> 6) & 7;
            int hd = col & 63;
            #pragma unroll
            for (int mt = 0; mt < MF; ++mt) {
                int row0 = bm + wr*(BM/2) + mt*16 + qd*4;
                int bb = row0 >> 9, t = row0 & 511;
                s16x4 v4;
                #pragma unroll
                for (int r = 0; r < 4; ++r) {
                    bf16 cb = __float2bfloat16(acc[mt][nt][r] + bv);
                    v4[r] = *reinterpret_cast<short*>(&cb);
                }
                *(s16x4*)(VTout + ((size_t)((bb*8 + hh)*64 + hd))*512 + t) = v4;
            }
        }
        return;
    }

    const float alp = PRELU ? alpha[aidx] : 0.f;
    fp32p bsel = bias;
    if (BIAS == 3) bsel = (bn < 512) ? bias : ((bn < 1024) ? bias2 : bias3);
    #pragma unroll
    for (int nt = 0; nt < NF; ++nt) {
        int col = bn + wc*(BN/2) + nt*16 + cl;
        if (col < N) {
            float bv = 0.f;
            if (BIAS == 1) bv = bsel[biasoff + col];
            if (BIAS == 3) bv = bsel[biasoff + (col & 511)];
            #pragma unroll
            for (int mt = 0; mt < MF; ++mt) {
                #pragma unroll
                for (int r = 0; r < 4; ++r) {
                    int row = bm + wr*(BM/2) + mt*16 + qd*4 + r;
                    float c = acc[mt][nt][r] + bv;
                    if (PRELU) c = (c >= 0.f) ? c : alp*c;
                    if (RESID) c += resid[(size_t)row*ldc + col];
                    if (OUTM == 0) {
                        ((bf16*)Cout)[(size_t)row*ldc + col] = __float2bfloat16(c);
                    } else if (OUTM == 1) {
                        ((float*)Cout)[(size_t)row*ldc + col] = c;
                    } else if (OUTM == 2) {
                        ((float*)Cout)[(size_t)row*ldc + col] = c;
                        VTout[(size_t)row*ldc + col] = __float2bfloat16(c);
                    } else {   // OUTM == 3: decoder split + sigmoid, Cout = final output
                        float* op = (float*)Cout;
                        if (col < DOF) op[(size_t)row*DOF + col] = c;
                        else op[(size_t)MTOK*DOF + (size_t)row*4 + (col - DOF)] = 1.f/(1.f + expf(-c));
                    }
                }
            }
        }
    }
}

// ---------------- LayerNorm: fp32 in -> bf16 out (shuffle reduce, 1 barrier) ----------
__global__ __launch_bounds__(256)
void k_layernorm(const float* __restrict__ x, fp32p g, fp32p b, bf16* __restrict__ out){
    __shared__ float part[8];
    const int row = blockIdx.x, tid = threadIdx.x;
    const int w = tid >> 6, lane = tid & 63;
    const float* xr = x + (size_t)row*DMODEL;
    float x0 = xr[tid], x1 = xr[tid+256];
    float s = x0 + x1, s2 = x0*x0 + x1*x1;
    #pragma unroll
    for (int o = 1; o < 64; o <<= 1) {
        s  += __shfl_xor(s,  o);
        s2 += __shfl_xor(s2, o);
    }
    if (lane == 0) { part[w] = s; part[4+w] = s2; }
    __syncthreads();
    float ts  = part[0] + part[1] + part[2] + part[3];
    float ts2 = part[4] + part[5] + part[6] + part[7];
    float mean = ts * (1.f/DMODEL);
    float var  = ts2 * (1.f/DMODEL) - mean*mean;
    float inv  = rsqrtf(var + 1e-6f);
    out[(size_t)row*DMODEL + tid]     = __float2bfloat16((x0 - mean)*inv*g[tid]     + b[tid]);
    out[(size_t)row*DMODEL + tid+256] = __float2bfloat16((x1 - mean)*inv*g[tid+256] + b[tid+256]);
}

// ---------------- relative embedding E: (EROWS, HD) bf16, zero-padded ----------------
__global__ __launch_bounds__(64)
void k_relemb(fp32p w1, fp32p b1, fp32p a, fp32p w2, fp32p b2, bf16* __restrict__ Ebf){
    __shared__ float sH[DMODEL];
    const int r = blockIdx.x, tid = threadIdx.x;
    if (r >= 2*TT - 1) { Ebf[(size_t)r*HD + tid] = __float2bfloat16(0.f); return; }
    const float dist = (float)(r - (TT-1));
    const float al = a[0];
    for (int d = tid; d < DMODEL; d += 64) {
        float hv = dist * w1[d] + b1[d];
        sH[d] = (hv >= 0.f) ? hv : al*hv;
    }
    __syncthreads();
    float acc = b2[tid];
    for (int d = 0; d < DMODEL; ++d) acc += sH[d] * w2[(size_t)d*HD + tid];
    Ebf[(size_t)r*HD + tid] = __float2bfloat16(acc);
}

// ---------------- MFMA flash attention with relative-position skew ----------------
// 512 threads = 8 waves; block owns 128 q-rows (grid = 256 = 1/CU). Block stages
// K/V^T/E-window per J-tile via coalesced global_load_lds double buffers (8-chunk XOR
// swizzle), one iteration ahead. One barrier per J-tile. Row-sum via MFMA-with-ones.
__global__ __launch_bounds__(512)
void k_attn(bf16p q, bf16p k, bf16p VT, bf16p Ebf, bf16* __restrict__ o, int qp)
{
    __shared__ __attribute__((aligned(16))) bf16 sK[2][64*64];    // 16 KB
    __shared__ __attribute__((aligned(16))) bf16 sV[2][64*64];    // 16 KB
    __shared__ __attribute__((aligned(16))) bf16 sE[2][208*64];   // 52 KB
    __shared__ float sQE[8][16][100];                             // 50 KB
    __shared__ __attribute__((aligned(16))) bf16 sP[8][16*64];    // 16 KB

    const int bid = blockIdx.x;
    const int it2 = bid >> 6;          // 0..3 in high bits: same-(b,h) group on one XCD
    const int h   = bid & 7;
    const int b   = (bid >> 3) & 7;
    const int tid = threadIdx.x;
    const int w   = tid >> 6;          // 0..7
    const int lane= tid & 63;
    const int qd  = lane >> 4;
    const int cl  = lane & 15;

    const int I = it2*128 + w*16;
    const size_t bh   = ((size_t)b*TT)*qp + (size_t)h*HD;
    const size_t boff = ((size_t)b*TT)*DMODEL + (size_t)h*HD;

    const int srow = tid >> 3, sch = tid & 7;
    const int ssc  = sch ^ (srow & 7);
    const int ldso = srow*64 + sch*8;              // == tid*16 bytes, linear
    const bf16* kg = k  + bh + (size_t)srow*qp + ssc*8;
    const bf16* vg = VT + ((size_t)((b*8 + h)*64 + srow))*512 + ssc*8;
    const int ebase0 = 384 - it2*128;              // E window base = J + ebase0

    auto stage = [&](int p, int J){
        gload16(kg + (size_t)J*qp, &sK[p][ldso]);
        gload16(vg + J,            &sV[p][ldso]);
        const bf16* eg = Ebf + (size_t)(J + ebase0 + srow)*HD + ssc*8;
        gload16(eg,          &sE[p][ldso]);
        gload16(eg + 64*HD,  &sE[p][ldso + 64*64]);
        gload16(eg + 128*HD, &sE[p][ldso + 128*64]);
        if (tid < 128) gload16(eg + 192*HD, &sE[p][ldso + 192*64]);   // rows 192..207
    };

    bf16x8 qa0, qa1, ones;
    {
        const bf16* qrow = q + bh + (size_t)(I + cl)*qp;
        qa0 = *(const bf16x8*)(qrow + qd*8);
        qa1 = *(const bf16x8*)(qrow + 32 + qd*8);
    }
    #pragma unroll
    for (int e = 0; e < 8; ++e) ((short*)&ones)[e] = 0x3F80;   // bf16 1.0

    f32x4 Oacc[4] = {};
    float m_i[4], l_i[4];
    #pragma unroll
    for (int r = 0; r < 4; ++r) { m_i[r] = -1e30f; l_i[r] = 0.f; }
    const float scale = 0.125f;

    const int c0 = (qd ^ (cl & 7))*8;
    const int c1 = ((qd ^ (cl & 7)) ^ 4)*8;
    const int erow0 = 112 - w*16;       // wave's E-window offset within block window

    stage(0, 0);
    int p = 0;

    for (int J = 0; J < TT; J += 64) {
        __syncthreads();                       // buf[p] staged & prev reads done
        if (J + 64 < TT) stage(p^1, J + 64);   // next tile flies under this iteration

        // ---- QK^T from sK ----
        f32x4 S[4];
        #pragma unroll
        for (int js = 0; js < 4; ++js) {
            const bf16* kr = &sK[p][(js*16 + cl)*64];
            bf16x8 kb0 = *(const bf16x8*)(kr + c0);
            bf16x8 kb1 = *(const bf16x8*)(kr + c1);
            f32x4 acc = {};
            acc = __builtin_amdgcn_mfma_f32_16x16x32_bf16(qa0, kb0, acc, 0, 0, 0);
            acc = __builtin_amdgcn_mfma_f32_16x16x32_bf16(qa1, kb1, acc, 0, 0, 0);
            S[js] = acc;
        }

        // ---- QE from sE ----
        #pragma unroll
        for (int nt = 0; nt < 6; ++nt) {
            const bf16* er = &sE[p][(erow0 + nt*16 + cl)*64];
            bf16x8 eb0 = *(const bf16x8*)(er + c0);
            bf16x8 eb1 = *(const bf16x8*)(er + c1);
            f32x4 acc = {};
            acc = __builtin_amdgcn_mfma_f32_16x16x32_bf16(qa0, eb0, acc, 0, 0, 0);
            acc = __builtin_amdgcn_mfma_f32_16x16x32_bf16(qa1, eb1, acc, 0, 0, 0);
            #pragma unroll
            for (int r = 0; r < 4; ++r)
                sQE[w][qd*4 + r][nt*16 + cl] = acc[r];
        }

        // ---- skew add + online softmax ----
        float mnew[4];
        #pragma unroll
        for (int r = 0; r < 4; ++r) mnew[r] = m_i[r];
        #pragma unroll
        for (int js = 0; js < 4; ++js) {
            #pragma unroll
            for (int r = 0; r < 4; ++r) {
                int idx = js*16 + cl - (qd*4 + r) + 15;
                float s = S[js][r] + sQE[w][qd*4 + r][idx];
                S[js][r] = s;
                mnew[r] = fmaxf(mnew[r], s);
            }
        }
        #pragma unroll
        for (int r = 0; r < 4; ++r) {
            float mv = mnew[r];
            mv = fmaxf(mv, __shfl_xor(mv, 1));
            mv = fmaxf(mv, __shfl_xor(mv, 2));
            mv = fmaxf(mv, __shfl_xor(mv, 4));
            mv = fmaxf(mv, __shfl_xor(mv, 8));
            mnew[r] = mv;
        }
        float alpha[4];
        #pragma unroll
        for (int r = 0; r < 4; ++r) {
            alpha[r] = __expf((m_i[r] - mnew[r]) * scale);
            m_i[r] = mnew[r];
        }
        // P -> per-wave LDS [16][64], chunk ^ (row&7) swizzle
        #pragma unroll
        for (int js = 0; js < 4; ++js) {
            #pragma unroll
            for (int r = 0; r < 4; ++r) {
                float pv = __expf((S[js][r] - m_i[r]) * scale);
                int prow = qd*4 + r;
                int pcol = ((js*2 + (cl >> 3)) ^ (prow & 7))*8 + (cl & 7);
                sP[w][prow*64 + pcol] = __float2bfloat16(pv);
            }
        }

        // P fragments: aligned b128 with the same involution
        bf16x8 pa0, pa1;
        {
            const bf16* pb = &sP[w][cl*64];
            pa0 = *(const bf16x8*)(pb + c0);
            pa1 = *(const bf16x8*)(pb + c1);
        }

        // row-sum of P via MFMA against ones
        {
            f32x4 lacc = {};
            lacc = __builtin_amdgcn_mfma_f32_16x16x32_bf16(pa0, ones, lacc, 0, 0, 0);
            lacc = __builtin_amdgcn_mfma_f32_16x16x32_bf16(pa1, ones, lacc, 0, 0, 0);
            #pragma unroll
            for (int r = 0; r < 4; ++r) l_i[r] = l_i[r]*alpha[r] + lacc[r];
        }

        // ---- PV from sV ----
        #pragma unroll
        for (int nt = 0; nt < 4; ++nt) {
            #pragma unroll
            for (int r = 0; r < 4; ++r) Oacc[nt][r] *= alpha[r];
            const bf16* vr = &sV[p][(nt*16 + cl)*64];
            bf16x8 vb0 = *(const bf16x8*)(vr + c0);
            bf16x8 vb1 = *(const bf16x8*)(vr + c1);
            Oacc[nt] = __builtin_amdgcn_mfma_f32_16x16x32_bf16(pa0, vb0, Oacc[nt], 0, 0, 0);
            Oacc[nt] = __builtin_amdgcn_mfma_f32_16x16x32_bf16(pa1, vb1, Oacc[nt], 0, 0, 0);
        }
        p ^= 1;
    }

    #pragma unroll
    for (int nt = 0; nt < 4; ++nt) {
        #pragma unroll
        for (int r = 0; r < 4; ++r) {
            int row = qd*4 + r;
            float val = Oacc[nt][r] / l_i[r];
            o[boff + (size_t)(I + row)*DMODEL + nt*16 + cl] = __float2bfloat16(val);
        }
    }
}

extern "C" void kernel_launch(void* const* d_in, const int* in_sizes, int n_in,
                              void* d_out, int out_size, void* d_ws, size_t ws_size,
                              hipStream_t stream)
{
    fp32p x      = (fp32p)d_in[0];
    fp32p mask   = (fp32p)d_in[1];
    fp32p enc_w1 = (fp32p)d_in[2];
    fp32p enc_b1 = (fp32p)d_in[3];
    fp32p enc_a1 = (fp32p)d_in[4];
    fp32p enc_w2 = (fp32p)d_in[5];
    fp32p enc_b2 = (fp32p)d_in[6];
    fp32p enc_a2 = (fp32p)d_in[7];
    fp32p rel_w1 = (fp32p)d_in[8];
    fp32p rel_b1 = (fp32p)d_in[9];
    fp32p rel_a  = (fp32p)d_in[10];
    fp32p rel_w2 = (fp32p)d_in[11];
    fp32p rel_b2 = (fp32p)d_in[12];
    fp32p ln_g   = (fp32p)d_in[13];
    fp32p ln_b   = (fp32p)d_in[14];
    fp32p wq     = (fp32p)d_in[15];
    fp32p bq     = (fp32p)d_in[16];
    fp32p wk     = (fp32p)d_in[17];
    fp32p bk     = (fp32p)d_in[18];
    fp32p wv     = (fp32p)d_in[19];
    fp32p bv     = (fp32p)d_in[20];
    fp32p wo     = (fp32p)d_in[21];
    fp32p bo     = (fp32p)d_in[22];
    fp32p fw1    = (fp32p)d_in[23];
    fp32p fb1    = (fp32p)d_in[24];
    fp32p fa     = (fp32p)d_in[25];
    fp32p fw2    = (fp32p)d_in[26];
    fp32p fb2    = (fp32p)d_in[27];
    fp32p dec_w1 = (fp32p)d_in[28];
    fp32p dec_b1 = (fp32p)d_in[29];
    fp32p dec_a  = (fp32p)d_in[30];
    fp32p dec_w2 = (fp32p)d_in[31];
    fp32p dec_b2 = (fp32p)d_in[32];

    char* wsb = (char*)d_ws;
    bf16*  Ebf  = (bf16*)(wsb + E_OFF);
    float* h    = (float*)(wsb + H_OFF);
    bf16*  hn   = (bf16*)(wsb + HN_OFF);
    bf16*  qkb  = (bf16*)(wsb + QKV_OFF);             // 4096 x 1024 bf16 (q|k fused)
    bf16*  VTb  = qkb + (size_t)MTOK*QKP;             // 64bh x 64d x 512t bf16 (4MB)
    bf16*  mid  = qkb;                      // ffn mid 4096 x 2048 bf16 (aliases qk+VT)
    bf16*  cat  = qkb;                      // encoder scratch (pitch CATP)

    // transposed bf16 weights: 6 layers upfront + enc/dec tail region
    bf16* lwt = (bf16*)(wsb + WT_OFF);               // 6 x LWT_ELEMS
    bf16* ed  = lwt + 6*LWT_ELEMS;                   // enc1|enc2|dec1|dec2
    bf16* enc1T = ed;                                // 512 x 192 (zero-padded K)
    bf16* enc2T = ed + 512*CATP;                     // 512 x 512
    bf16* dec1T = enc2T + 262144;                    // 512 x 512
    bf16* dec2T = dec1T + 262144;                    // 73 x 512
    bf16* hb  = lwt;        // decoder bf16 h (4MB) — overlays layer-0 weights (dead by then;
                            // k_wtall rewrites them at the start of every launch/replay)

    dim3 g512(8, 128);     // N=512: BM=32 BN=64  -> 1024 blocks (4/CU, 4 waves/SIMD)
    dim3 gQKV(12, 128);    // N=1536: BM=32 BN=128 -> 1536 blocks (LDS-capped 4/CU)
    dim3 gF1(16, 128);     // N=2048: BM=32 BN=128 -> 2048 blocks (LDS-capped 4/CU)

    // ALL weight transposes in one dispatch, then encoder
    k_wtall<<<4776, 256, 0, stream>>>(wq, wk, wv, wo, fw1, fw2,
                                      enc_w1, enc_w2, dec_w1, dec_w2, lwt, ed);
    k_concat<<<(MTOK*CATP+255)/256, 256, 0, stream>>>(x, mask, cat);
    k_gemm<32,64,1,0,1,0,0><<<g512,256,0,stream>>>(cat, CATP, enc1T, CATP, enc_b1, nullptr, nullptr, 0, enc_a1, 0, nullptr, hn, DMODEL, nullptr, MTOK, DMODEL, CATP);
    k_gemm<32,64,1,0,1,1,0><<<g512,256,0,stream>>>(hn, DMODEL, enc2T, DMODEL, enc_b2, nullptr, nullptr, 0, enc_a2, 0, nullptr, h, DMODEL, nullptr, MTOK, DMODEL, DMODEL);
    k_relemb<<<EROWS, 64, 0, stream>>>(rel_w1, rel_b1, rel_a, rel_w2, rel_b2, Ebf);

    for (int l = 0; l < NL; ++l) {
        size_t oB  = (size_t)l*DMODEL;
        size_t oBF1= (size_t)l*DFF;
        bf16* Lw = lwt + (size_t)l*LWT_ELEMS;

        k_layernorm<<<MTOK, 256, 0, stream>>>(h, ln_g, ln_b, hn);
        // fused QKV: N=1536; q|k -> qkb (pitch 1024), v -> VTb transposed
        k_gemm<32,128,0,0,3,0,1><<<gQKV,256,0,stream>>>(hn, DMODEL, Lw, DMODEL, bq, bk, bv, oB, nullptr, 0, nullptr, qkb, QKP, VTb, MTOK, 1536, DMODEL);
        k_attn<<<BB*NH*(TT/128), 512, 0, stream>>>(qkb, qkb + 512, VTb, Ebf, hn, QKP);
        k_gemm<32,64,0,1,1,1,0><<<g512,256,0,stream>>>(hn, DMODEL, Lw + 786432, DMODEL, bo, nullptr, nullptr, oB, nullptr, 0, h, h, DMODEL, nullptr, MTOK, DMODEL, DMODEL);
        k_layernorm<<<MTOK, 256, 0, stream>>>(h, ln_g, ln_b, hn);
        // fused FFN: f1 full N=2048 -> mid; f2 full K=2048 -> h (+resid)
        k_gemm<32,128,1,0,1,0,0><<<gF1,256,0,stream>>>(hn, DMODEL, Lw + 1048576, DMODEL, fb1, nullptr, nullptr, oBF1, fa, (size_t)l, nullptr, mid, DFF, nullptr, MTOK, DFF, DMODEL);
        if (l == NL-1)   // dual-output: h fp32 + hb bf16 (replaces k_cast)
            k_gemm<32,64,0,1,1,2,0><<<g512,256,0,stream>>>(mid, DFF, Lw + 2097152, DFF, fb2, nullptr, nullptr, oB, nullptr, 0, h, h, DMODEL, hb, MTOK, DMODEL, DFF);
        else
            k_gemm<32,64,0,1,1,1,0><<<g512,256,0,stream>>>(mid, DFF, Lw + 2097152, DFF, fb2, nullptr, nullptr, oB, nullptr, 0, h, h, DMODEL, nullptr, MTOK, DMODEL, DFF);
    }

    // decoder (k_cast and k_out fused into GEMM epilogues)
    k_gemm<32,64,1,0,1,0,0><<<g512,256,0,stream>>>(hb, DMODEL, dec1T, DMODEL, dec_b1, nullptr, nullptr, 0, dec_a, 0, nullptr, hn, DMODEL, nullptr, MTOK, DMODEL, DMODEL);
    {
        dim3 g2(2, 128);   // N=73: BN=64 -> 2 col tiles, BM=32 -> 256 blocks
        k_gemm<32,64,0,0,1,3,0><<<g2,256,0,stream>>>(hn, DMODEL, dec2T, DMODEL, dec_b2, nullptr, nullptr, 0, nullptr, 0, nullptr, d_out, DOF, nullptr, MTOK, DOF+4, DMODEL);
    }
}

// Round 13
// 789.283 us; speedup vs baseline: 1.0594x; 1.0594x over previous
//
#include <hip/hip_runtime.h>
#include <hip/hip_bf16.h>

#define DOF 69
#define NL 6
#define NH 8
#define DMODEL 512
#define DFF 2048
#define HD 64
#define BB 8
#define TT 512
#define MTOK (BB*TT)   // 4096
#define EROWS 1040     // 2T-1 = 1023, padded
#define CATP 192       // padded concat pitch (K=138 rounded to 64)
#define QKP 1024       // fused q|k row pitch (v split out transposed)

// workspace layout (bytes) — ~75 MB total (harness ws >= 256 MB per fill traces)
#define E_OFF     4096u
#define H_OFF     (512u*1024u)
#define HN_OFF    (H_OFF + 8u*1024u*1024u)
#define QKV_OFF   (HN_OFF + 4u*1024u*1024u)      // 16 MB region: qk(8MB)+VT(4MB) / mid(16MB) / scratch
#define WT_OFF    (QKV_OFF + 16u*1024u*1024u)    // 36 MB: 6 layers of bf16 B^T weights + enc/dec tail
#define LWT_ELEMS 3145728u                       // per-layer bf16 elems (qkv|wo|f1|f2)

typedef const float* fp32p;
typedef __hip_bfloat16 bf16;
typedef const bf16* bf16p;
typedef __attribute__((ext_vector_type(8))) short bf16x8;  // 8 bf16 (4 VGPRs)
typedef __attribute__((ext_vector_type(4))) short s16x4;   // 4 bf16 (8B store)
typedef __attribute__((ext_vector_type(4))) float f32x4;   // 4 fp32 acc

typedef __attribute__((address_space(1))) const void as1_cvoid;
typedef __attribute__((address_space(3))) void       as3_void;

__device__ __forceinline__ void gload16(const bf16* g, const bf16* l){
    __builtin_amdgcn_global_load_lds((as1_cvoid*)g, (as3_void*)l, 16, 0, 0);
}

__device__ __forceinline__ float b2f(bf16 x){ return __bfloat162float(x); }

// ---------------- concat(x, mask) fp32 -> bf16, zero-padded to pitch CATP ----------------
__global__ __launch_bounds__(256)
void k_concat(fp32p x, fp32p mask, bf16* __restrict__ out){
    int idx = blockIdx.x*256 + threadIdx.x;
    if (idx >= MTOK*CATP) return;
    int row = idx / CATP, c = idx - row*CATP;
    float v = 0.f;
    if (c < DOF) v = x[(size_t)row*DOF + c];
    else if (c < 2*DOF) v = mask[(size_t)row*DOF + (c - DOF)];
    out[idx] = __float2bfloat16(v);
}

// ---------------- ALL weight transposes (6 layers + enc + dec) in ONE dispatch ----------
// 64x64 tiles: float4 reads (coalesced 1KB/wave) + short8 FULL-LINE writes (one 128B
// line per n-row) -> no partial-line write amplification.
__global__ __launch_bounds__(256)
void k_wtall(fp32p wq, fp32p wk, fp32p wv, fp32p wo, fp32p fw1, fp32p fw2,
             fp32p enc_w1, fp32p enc_w2, fp32p dec_w1, fp32p dec_w2,
             bf16* __restrict__ lwt, bf16* __restrict__ ed)
{
    __shared__ float s[64][65];
    const int t = blockIdx.x;
    const int tid = threadIdx.x;

    if (t < 4608) {
        const int l = t / 768, u = t - l*768;
        bf16* base = lwt + (size_t)l*LWT_ELEMS;
        fp32p src; bf16* dst; int N, ldk, k0, n0;
        if (u < 256) {
            int seg = u >> 6, local = u & 63;
            N = 512; ldk = 512;
            k0 = (local & 7) * 64; n0 = (local >> 3) * 64;
            size_t oW = (size_t)l*512*512;
            if      (seg == 0) { src = wq + oW; dst = base; }
            else if (seg == 1) { src = wk + oW; dst = base + 262144; }
            else if (seg == 2) { src = wv + oW; dst = base + 524288; }
            else               { src = wo + oW; dst = base + 786432; }
        } else if (u < 512) {
            int local = u - 256;
            N = 2048; ldk = 512;
            k0 = (local & 7) * 64; n0 = (local >> 3) * 64;
            src = fw1 + (size_t)l*512*2048; dst = base + 1048576;
        } else {
            int local = u - 512;
            N = 512; ldk = 2048;
            k0 = (local >> 3) * 64; n0 = (local & 7) * 64;
            src = fw2 + (size_t)l*2048*512; dst = base + 2097152;
        }
        #pragma unroll
        for (int j = 0; j < 4; ++j) {
            int idx = j*256 + tid;
            int row = idx >> 4, cq = idx & 15;
            float4 v = *(const float4*)(src + (size_t)(k0+row)*N + n0 + cq*4);
            s[row][cq*4+0] = v.x; s[row][cq*4+1] = v.y;
            s[row][cq*4+2] = v.z; s[row][cq*4+3] = v.w;
        }
        __syncthreads();
        #pragma unroll
        for (int j = 0; j < 2; ++j) {
            int idx = j*256 + tid;
            int n = idx >> 3, oct = idx & 7;
            bf16x8 pack;
            #pragma unroll
            for (int e = 0; e < 8; ++e) {
                bf16 cb = __float2bfloat16(s[oct*8 + e][n]);
                ((short*)&pack)[e] = *reinterpret_cast<short*>(&cb);
            }
            *(bf16x8*)(dst + (size_t)(n0+n)*ldk + k0 + oct*8) = pack;
        }
        return;
    }

    // guarded tail: enc/dec (few blocks, scalar path)
    int t2 = t - 4608;
    fp32p src; bf16* dst; int K, N, ldk, k0, n0;
    if (t2 < 24)       { src = enc_w1; dst = ed;          K = 2*DOF; N = 512; ldk = CATP; k0 = (t2 % 3)*64; n0 = (t2 / 3)*64; }
    else if (t2 < 88)  { int lx = t2 - 24;  src = enc_w2; dst = ed + 512*CATP;          K = 512; N = 512;   ldk = 512; k0 = (lx & 7)*64; n0 = (lx >> 3)*64; }
    else if (t2 < 152) { int lx = t2 - 88;  src = dec_w1; dst = ed + 512*CATP + 262144; K = 512; N = 512;   ldk = 512; k0 = (lx & 7)*64; n0 = (lx >> 3)*64; }
    else               { int lx = t2 - 152; src = dec_w2; dst = ed + 512*CATP + 524288; K = 512; N = DOF+4; ldk = 512; k0 = (lx >> 1)*64; n0 = (lx & 1)*64; }
    for (int idx = tid; idx < 4096; idx += 256) {
        int row = idx >> 6, c = idx & 63;
        int k = k0 + row, n = n0 + c;
        s[row][c] = (k < K && n < N) ? src[(size_t)k*N + n] : 0.f;
    }
    __syncthreads();
    for (int idx = tid; idx < 4096; idx += 256) {
        int n = idx >> 6, c = idx & 63;
        if (n0 + n < N) dst[(size_t)(n0+n)*ldk + k0 + c] = __float2bfloat16(s[c][n]);
    }
}

// ---------------- LDS-tiled MFMA GEMM (proven __syncthreads 2-phase, BK templated) ----
// C = epi(A @ B + bias); A bf16 (M x K) lda; BT bf16 (N x ldk) = B^T.
// Block = 256 threads (4 waves, 2x2 wave grid), tile BM x BN, K-slab BK (64 or 128).
// BK=128 halves the per-GEMM barrier-drain count and doubles MFMA/barrier (16/wave)
// with LDS 64KB -> still 2 blocks/CU for the N=512 family (grid-matched, so the
// m132 occupancy-loss failure mode does not apply). BK=64 kept where LDS (BN=128)
// or K%128!=0 (enc1) requires.
// Swizzle: CH=BK/8 chunks, involution chunk ^ (row & (CH-1)) on GLOBAL source and
// LDS READ (both-sides, rule #21); fragment rows satisfy row&(CH-1)==cl so reads
// stay aligned ds_read_b128 at the >=8-lane/slot floor (m136: free).
// XCD-aware chunked block swizzle (T1/m204). Requires K%BK==0, M%BM==0.
// BIAS: 0=none, 1=bias[], 3=segment-select of {bias,bias2,bias3} by col/512.
// OUTM: 0=bf16, 1=fp32, 2=fp32 Cout + bf16 dual-dst (VTout), 3=decoder split+sigmoid.
// SPLITV: blocks with bn>=1024 write transposed per-head VT[b][h][d][t] (QKV fusion).
template<int BM, int BN, int BK, int PRELU, int RESID, int BIAS, int OUTM, int SPLITV>
__global__ __launch_bounds__(256)
void k_gemm(bf16p A, int lda,
            bf16p BT, int ldk,
            fp32p bias, fp32p bias2, fp32p bias3, size_t biasoff,
            fp32p alpha, size_t aidx,
            const float* __restrict__ resid,
            void* __restrict__ Cout, int ldc,
            bf16* __restrict__ VTout,
            int M, int N, int K)
{
    constexpr int MF = BM/32;
    constexpr int NF = BN/32;
    constexpr int CH = BK/8;          // 16B chunks per row
    constexpr int CM = CH - 1;
    constexpr int RI = 512/BK;        // rows per wave stage-issue (64 lanes x 16B / row)
    constexpr int AI = BM/(4*RI);     // A stage issues per wave
    constexpr int BI = BN/(4*RI);     // B stage issues per wave

    __shared__ __attribute__((aligned(16))) bf16 sA[2][BM*BK];
    __shared__ __attribute__((aligned(16))) bf16 sB[2][BN*BK];

    // XCD-aware bijective swizzle (m204)
    int bx, by;
    {
        const int gx  = gridDim.x;
        const int nwg = gx * gridDim.y;
        const int bid = blockIdx.y * gx + blockIdx.x;
        const int qq = nwg >> 3, rr = nwg & 7;
        const int xcd = bid & 7, pos = bid >> 3;
        const int nb = (xcd < rr) ? (xcd*(qq+1) + pos) : (rr*(qq+1) + (xcd-rr)*qq + pos);
        bx = nb % gx; by = nb / gx;
    }

    const int tid  = threadIdx.x;
    const int w    = tid >> 6;
    const int lane = tid & 63;
    const int qd   = lane >> 4;
    const int cl   = lane & 15;
    const int wr   = w >> 1;
    const int wc   = w & 1;
    const int bm   = by * BM;
    const int bn   = bx * BN;

    const int srow = lane / CH;       // row within a stage-issue group
    const int sch  = lane & CM;       // LDS chunk this lane's 16B lands in

    f32x4 acc[MF][NF] = {};

    auto stage = [&](int p, int k0){
        #pragma unroll
        for (int i = 0; i < AI; ++i) {
            int rl = w*(BM/4) + i*RI + srow;               // LDS row
            int sc = sch ^ (rl & CM);                      // global source chunk
            gload16(A + (size_t)(bm + rl)*lda + k0 + sc*8, &sA[p][(w*(BM/4) + i*RI)*BK]);
        }
        #pragma unroll
        for (int i = 0; i < BI; ++i) {
            int rl = w*(BN/4) + i*RI + srow;
            int sc = sch ^ (rl & CM);
            int rg = min(bn + rl, N-1);
            gload16(BT + (size_t)rg*ldk + k0 + sc*8, &sB[p][(w*(BN/4) + i*RI)*BK]);
        }
    };

    stage(0, 0);
    int p = 0;
    for (int k0 = 0; k0 < K; k0 += BK) {
        __syncthreads();                       // drains vmcnt: buf[p] ready
        if (k0 + BK < K) stage(p^1, k0 + BK);  // issue next slab under compute
        #pragma unroll
        for (int ks = 0; ks < BK/32; ++ks) {
            const int rcc = ks*4 + qd;
            bf16x8 aF[MF], bF[NF];
            #pragma unroll
            for (int mt = 0; mt < MF; ++mt) {
                int row = wr*(BM/2) + mt*16 + cl;          // row & CM == cl & CM
                aF[mt] = *(const bf16x8*)(&sA[p][row*BK + ((rcc ^ (cl & CM))*8)]);
            }
            #pragma unroll
            for (int nt = 0; nt < NF; ++nt) {
                int row = wc*(BN/2) + nt*16 + cl;
                bF[nt] = *(const bf16x8*)(&sB[p][row*BK + ((rcc ^ (cl & CM))*8)]);
            }
            #pragma unroll
            for (int mt = 0; mt < MF; ++mt)
                #pragma unroll
                for (int nt = 0; nt < NF; ++nt)
                    acc[mt][nt] = __builtin_amdgcn_mfma_f32_16x16x32_bf16(aF[mt], bF[nt], acc[mt][nt], 0, 0, 0);
        }
        p ^= 1;
    }

    if (SPLITV && bn >= 1024) {
        // V segment: write transposed VT[((b*8+h)*64+hd)*512 + t], 8B short4 stores
        #pragma unroll
        for (int nt = 0; nt < NF; ++nt) {
            int col = bn + wc*(BN/2) + nt*16 + cl;
            float bv = bias3[biasoff + (col & 511)];
            int hh = (col >> 6) & 7;
            int hd = col & 63;
            #pragma unroll
            for (int mt = 0; mt < MF; ++mt) {
                int row0 = bm + wr*(BM/2) + mt*16 + qd*4;
                int bb = row0 >> 9, t = row0 & 511;
                s16x4 v4;
                #pragma unroll
                for (int r = 0; r < 4; ++r) {
                    bf16 cb = __float2bfloat16(acc[mt][nt][r] + bv);
                    v4[r] = *reinterpret_cast<short*>(&cb);
                }
                *(s16x4*)(VTout + ((size_t)((bb*8 + hh)*64 + hd))*512 + t) = v4;
            }
        }
        return;
    }

    const float alp = PRELU ? alpha[aidx] : 0.f;
    fp32p bsel = bias;
    if (BIAS == 3) bsel = (bn < 512) ? bias : ((bn < 1024) ? bias2 : bias3);
    #pragma unroll
    for (int nt = 0; nt < NF; ++nt) {
        int col = bn + wc*(BN/2) + nt*16 + cl;
        if (col < N) {
            float bv = 0.f;
            if (BIAS == 1) bv = bsel[biasoff + col];
            if (BIAS == 3) bv = bsel[biasoff + (col & 511)];
            #pragma unroll
            for (int mt = 0; mt < MF; ++mt) {
                #pragma unroll
                for (int r = 0; r < 4; ++r) {
                    int row = bm + wr*(BM/2) + mt*16 + qd*4 + r;
                    float c = acc[mt][nt][r] + bv;
                    if (PRELU) c = (c >= 0.f) ? c : alp*c;
                    if (RESID) c += resid[(size_t)row*ldc + col];
                    if (OUTM == 0) {
                        ((bf16*)Cout)[(size_t)row*ldc + col] = __float2bfloat16(c);
                    } else if (OUTM == 1) {
                        ((float*)Cout)[(size_t)row*ldc + col] = c;
                    } else if (OUTM == 2) {
                        ((float*)Cout)[(size_t)row*ldc + col] = c;
                        VTout[(size_t)row*ldc + col] = __float2bfloat16(c);
                    } else {   // OUTM == 3: decoder split + sigmoid, Cout = final output
                        float* op = (float*)Cout;
                        if (col < DOF) op[(size_t)row*DOF + col] = c;
                        else op[(size_t)MTOK*DOF + (size_t)row*4 + (col - DOF)] = 1.f/(1.f + expf(-c));
                    }
                }
            }
        }
    }
}

// ---------------- LayerNorm: fp32 in -> bf16 out (shuffle reduce, 1 barrier) ----------
__global__ __launch_bounds__(256)
void k_layernorm(const float* __restrict__ x, fp32p g, fp32p b, bf16* __restrict__ out){
    __shared__ float part[8];
    const int row = blockIdx.x, tid = threadIdx.x;
    const int w = tid >> 6, lane = tid & 63;
    const float* xr = x + (size_t)row*DMODEL;
    float x0 = xr[tid], x1 = xr[tid+256];
    float s = x0 + x1, s2 = x0*x0 + x1*x1;
    #pragma unroll
    for (int o = 1; o < 64; o <<= 1) {
        s  += __shfl_xor(s,  o);
        s2 += __shfl_xor(s2, o);
    }
    if (lane == 0) { part[w] = s; part[4+w] = s2; }
    __syncthreads();
    float ts  = part[0] + part[1] + part[2] + part[3];
    float ts2 = part[4] + part[5] + part[6] + part[7];
    float mean = ts * (1.f/DMODEL);
    float var  = ts2 * (1.f/DMODEL) - mean*mean;
    float inv  = rsqrtf(var + 1e-6f);
    out[(size_t)row*DMODEL + tid]     = __float2bfloat16((x0 - mean)*inv*g[tid]     + b[tid]);
    out[(size_t)row*DMODEL + tid+256] = __float2bfloat16((x1 - mean)*inv*g[tid+256] + b[tid+256]);
}

// ---------------- relative embedding E: (EROWS, HD) bf16, zero-padded ----------------
__global__ __launch_bounds__(64)
void k_relemb(fp32p w1, fp32p b1, fp32p a, fp32p w2, fp32p b2, bf16* __restrict__ Ebf){
    __shared__ float sH[DMODEL];
    const int r = blockIdx.x, tid = threadIdx.x;
    if (r >= 2*TT - 1) { Ebf[(size_t)r*HD + tid] = __float2bfloat16(0.f); return; }
    const float dist = (float)(r - (TT-1));
    const float al = a[0];
    for (int d = tid; d < DMODEL; d += 64) {
        float hv = dist * w1[d] + b1[d];
        sH[d] = (hv >= 0.f) ? hv : al*hv;
    }
    __syncthreads();
    float acc = b2[tid];
    for (int d = 0; d < DMODEL; ++d) acc += sH[d] * w2[(size_t)d*HD + tid];
    Ebf[(size_t)r*HD + tid] = __float2bfloat16(acc);
}

// ---------------- MFMA flash attention with relative-position skew ----------------
// 512 threads = 8 waves; block owns 128 q-rows (grid = 256 = 1/CU). Block stages
// K/V^T/E-window per J-tile via coalesced global_load_lds double buffers (8-chunk XOR
// swizzle), one iteration ahead. One barrier per J-tile. Row-sum via MFMA-with-ones.
__global__ __launch_bounds__(512)
void k_attn(bf16p q, bf16p k, bf16p VT, bf16p Ebf, bf16* __restrict__ o, int qp)
{
    __shared__ __attribute__((aligned(16))) bf16 sK[2][64*64];    // 16 KB
    __shared__ __attribute__((aligned(16))) bf16 sV[2][64*64];    // 16 KB
    __shared__ __attribute__((aligned(16))) bf16 sE[2][208*64];   // 52 KB
    __shared__ float sQE[8][16][100];                             // 50 KB
    __shared__ __attribute__((aligned(16))) bf16 sP[8][16*64];    // 16 KB

    const int bid = blockIdx.x;
    const int it2 = bid >> 6;          // 0..3 in high bits: same-(b,h) group on one XCD
    const int h   = bid & 7;
    const int b   = (bid >> 3) & 7;
    const int tid = threadIdx.x;
    const int w   = tid >> 6;          // 0..7
    const int lane= tid & 63;
    const int qd  = lane >> 4;
    const int cl  = lane & 15;

    const int I = it2*128 + w*16;
    const size_t bh   = ((size_t)b*TT)*qp + (size_t)h*HD;
    const size_t boff = ((size_t)b*TT)*DMODEL + (size_t)h*HD;

    const int srow = tid >> 3, sch = tid & 7;
    const int ssc  = sch ^ (srow & 7);
    const int ldso = srow*64 + sch*8;              // == tid*16 bytes, linear
    const bf16* kg = k  + bh + (size_t)srow*qp + ssc*8;
    const bf16* vg = VT + ((size_t)((b*8 + h)*64 + srow))*512 + ssc*8;
    const int ebase0 = 384 - it2*128;              // E window base = J + ebase0

    auto stage = [&](int p, int J){
        gload16(kg + (size_t)J*qp, &sK[p][ldso]);
        gload16(vg + J,            &sV[p][ldso]);
        const bf16* eg = Ebf + (size_t)(J + ebase0 + srow)*HD + ssc*8;
        gload16(eg,          &sE[p][ldso]);
        gload16(eg + 64*HD,  &sE[p][ldso + 64*64]);
        gload16(eg + 128*HD, &sE[p][ldso + 128*64]);
        if (tid < 128) gload16(eg + 192*HD, &sE[p][ldso + 192*64]);   // rows 192..207
    };

    bf16x8 qa0, qa1, ones;
    {
        const bf16* qrow = q + bh + (size_t)(I + cl)*qp;
        qa0 = *(const bf16x8*)(qrow + qd*8);
        qa1 = *(const bf16x8*)(qrow + 32 + qd*8);
    }
    #pragma unroll
    for (int e = 0; e < 8; ++e) ((short*)&ones)[e] = 0x3F80;   // bf16 1.0

    f32x4 Oacc[4] = {};
    float m_i[4], l_i[4];
    #pragma unroll
    for (int r = 0; r < 4; ++r) { m_i[r] = -1e30f; l_i[r] = 0.f; }
    const float scale = 0.125f;

    const int c0 = (qd ^ (cl & 7))*8;
    const int c1 = ((qd ^ (cl & 7)) ^ 4)*8;
    const int erow0 = 112 - w*16;       // wave's E-window offset within block window

    stage(0, 0);
    int p = 0;

    for (int J = 0; J < TT; J += 64) {
        __syncthreads();                       // buf[p] staged & prev reads done
        if (J + 64 < TT) stage(p^1, J + 64);   // next tile flies under this iteration

        // ---- QK^T from sK ----
        f32x4 S[4];
        #pragma unroll
        for (int js = 0; js < 4; ++js) {
            const bf16* kr = &sK[p][(js*16 + cl)*64];
            bf16x8 kb0 = *(const bf16x8*)(kr + c0);
            bf16x8 kb1 = *(const bf16x8*)(kr + c1);
            f32x4 acc = {};
            acc = __builtin_amdgcn_mfma_f32_16x16x32_bf16(qa0, kb0, acc, 0, 0, 0);
            acc = __builtin_amdgcn_mfma_f32_16x16x32_bf16(qa1, kb1, acc, 0, 0, 0);
            S[js] = acc;
        }

        // ---- QE from sE ----
        #pragma unroll
        for (int nt = 0; nt < 6; ++nt) {
            const bf16* er = &sE[p][(erow0 + nt*16 + cl)*64];
            bf16x8 eb0 = *(const bf16x8*)(er + c0);
            bf16x8 eb1 = *(const bf16x8*)(er + c1);
            f32x4 acc = {};
            acc = __builtin_amdgcn_mfma_f32_16x16x32_bf16(qa0, eb0, acc, 0, 0, 0);
            acc = __builtin_amdgcn_mfma_f32_16x16x32_bf16(qa1, eb1, acc, 0, 0, 0);
            #pragma unroll
            for (int r = 0; r < 4; ++r)
                sQE[w][qd*4 + r][nt*16 + cl] = acc[r];
        }

        // ---- skew add + online softmax ----
        float mnew[4];
        #pragma unroll
        for (int r = 0; r < 4; ++r) mnew[r] = m_i[r];
        #pragma unroll
        for (int js = 0; js < 4; ++js) {
            #pragma unroll
            for (int r = 0; r < 4; ++r) {
                int idx = js*16 + cl - (qd*4 + r) + 15;
                float s = S[js][r] + sQE[w][qd*4 + r][idx];
                S[js][r] = s;
                mnew[r] = fmaxf(mnew[r], s);
            }
        }
        #pragma unroll
        for (int r = 0; r < 4; ++r) {
            float mv = mnew[r];
            mv = fmaxf(mv, __shfl_xor(mv, 1));
            mv = fmaxf(mv, __shfl_xor(mv, 2));
            mv = fmaxf(mv, __shfl_xor(mv, 4));
            mv = fmaxf(mv, __shfl_xor(mv, 8));
            mnew[r] = mv;
        }
        float alpha[4];
        #pragma unroll
        for (int r = 0; r < 4; ++r) {
            alpha[r] = __expf((m_i[r] - mnew[r]) * scale);
            m_i[r] = mnew[r];
        }
        // P -> per-wave LDS [16][64], chunk ^ (row&7) swizzle
        #pragma unroll
        for (int js = 0; js < 4; ++js) {
            #pragma unroll
            for (int r = 0; r < 4; ++r) {
                float pv = __expf((S[js][r] - m_i[r]) * scale);
                int prow = qd*4 + r;
                int pcol = ((js*2 + (cl >> 3)) ^ (prow & 7))*8 + (cl & 7);
                sP[w][prow*64 + pcol] = __float2bfloat16(pv);
            }
        }

        // P fragments: aligned b128 with the same involution
        bf16x8 pa0, pa1;
        {
            const bf16* pb = &sP[w][cl*64];
            pa0 = *(const bf16x8*)(pb + c0);
            pa1 = *(const bf16x8*)(pb + c1);
        }

        // row-sum of P via MFMA against ones
        {
            f32x4 lacc = {};
            lacc = __builtin_amdgcn_mfma_f32_16x16x32_bf16(pa0, ones, lacc, 0, 0, 0);
            lacc = __builtin_amdgcn_mfma_f32_16x16x32_bf16(pa1, ones, lacc, 0, 0, 0);
            #pragma unroll
            for (int r = 0; r < 4; ++r) l_i[r] = l_i[r]*alpha[r] + lacc[r];
        }

        // ---- PV from sV ----
        #pragma unroll
        for (int nt = 0; nt < 4; ++nt) {
            #pragma unroll
            for (int r = 0; r < 4; ++r) Oacc[nt][r] *= alpha[r];
            const bf16* vr = &sV[p][(nt*16 + cl)*64];
            bf16x8 vb0 = *(const bf16x8*)(vr + c0);
            bf16x8 vb1 = *(const bf16x8*)(vr + c1);
            Oacc[nt] = __builtin_amdgcn_mfma_f32_16x16x32_bf16(pa0, vb0, Oacc[nt], 0, 0, 0);
            Oacc[nt] = __builtin_amdgcn_mfma_f32_16x16x32_bf16(pa1, vb1, Oacc[nt], 0, 0, 0);
        }
        p ^= 1;
    }

    #pragma unroll
    for (int nt = 0; nt < 4; ++nt) {
        #pragma unroll
        for (int r = 0; r < 4; ++r) {
            int row = qd*4 + r;
            float val = Oacc[nt][r] / l_i[r];
            o[boff + (size_t)(I + row)*DMODEL + nt*16 + cl] = __float2bfloat16(val);
        }
    }
}

extern "C" void kernel_launch(void* const* d_in, const int* in_sizes, int n_in,
                              void* d_out, int out_size, void* d_ws, size_t ws_size,
                              hipStream_t stream)
{
    fp32p x      = (fp32p)d_in[0];
    fp32p mask   = (fp32p)d_in[1];
    fp32p enc_w1 = (fp32p)d_in[2];
    fp32p enc_b1 = (fp32p)d_in[3];
    fp32p enc_a1 = (fp32p)d_in[4];
    fp32p enc_w2 = (fp32p)d_in[5];
    fp32p enc_b2 = (fp32p)d_in[6];
    fp32p enc_a2 = (fp32p)d_in[7];
    fp32p rel_w1 = (fp32p)d_in[8];
    fp32p rel_b1 = (fp32p)d_in[9];
    fp32p rel_a  = (fp32p)d_in[10];
    fp32p rel_w2 = (fp32p)d_in[11];
    fp32p rel_b2 = (fp32p)d_in[12];
    fp32p ln_g   = (fp32p)d_in[13];
    fp32p ln_b   = (fp32p)d_in[14];
    fp32p wq     = (fp32p)d_in[15];
    fp32p bq     = (fp32p)d_in[16];
    fp32p wk     = (fp32p)d_in[17];
    fp32p bk     = (fp32p)d_in[18];
    fp32p wv     = (fp32p)d_in[19];
    fp32p bv     = (fp32p)d_in[20];
    fp32p wo     = (fp32p)d_in[21];
    fp32p bo     = (fp32p)d_in[22];
    fp32p fw1    = (fp32p)d_in[23];
    fp32p fb1    = (fp32p)d_in[24];
    fp32p fa     = (fp32p)d_in[25];
    fp32p fw2    = (fp32p)d_in[26];
    fp32p fb2    = (fp32p)d_in[27];
    fp32p dec_w1 = (fp32p)d_in[28];
    fp32p dec_b1 = (fp32p)d_in[29];
    fp32p dec_a  = (fp32p)d_in[30];
    fp32p dec_w2 = (fp32p)d_in[31];
    fp32p dec_b2 = (fp32p)d_in[32];

    char* wsb = (char*)d_ws;
    bf16*  Ebf  = (bf16*)(wsb + E_OFF);
    float* h    = (float*)(wsb + H_OFF);
    bf16*  hn   = (bf16*)(wsb + HN_OFF);
    bf16*  qkb  = (bf16*)(wsb + QKV_OFF);             // 4096 x 1024 bf16 (q|k fused)
    bf16*  VTb  = qkb + (size_t)MTOK*QKP;             // 64bh x 64d x 512t bf16 (4MB)
    bf16*  mid  = qkb;                      // ffn mid 4096 x 2048 bf16 (aliases qk+VT)
    bf16*  cat  = qkb;                      // encoder scratch (pitch CATP)

    // transposed bf16 weights: 6 layers upfront + enc/dec tail region
    bf16* lwt = (bf16*)(wsb + WT_OFF);               // 6 x LWT_ELEMS
    bf16* ed  = lwt + 6*LWT_ELEMS;                   // enc1|enc2|dec1|dec2
    bf16* enc1T = ed;                                // 512 x 192 (zero-padded K)
    bf16* enc2T = ed + 512*CATP;                     // 512 x 512
    bf16* dec1T = enc2T + 262144;                    // 512 x 512
    bf16* dec2T = dec1T + 262144;                    // 73 x 512
    bf16* hb  = lwt;        // decoder bf16 h (4MB) — overlays layer-0 weights (dead by then;
                            // k_wtall rewrites them at the start of every launch/replay)

    dim3 g512(8, 64);      // N=512: BM=64 BN=64  -> 512 blocks (2/CU)
    dim3 gQKV(12, 64);     // N=1536: BM=64 BN=128 -> 768 blocks (3/CU)
    dim3 gF1(16, 64);      // N=2048: BM=64 BN=128 -> 1024 blocks

    // ALL weight transposes in one dispatch, then encoder
    k_wtall<<<4776, 256, 0, stream>>>(wq, wk, wv, wo, fw1, fw2,
                                      enc_w1, enc_w2, dec_w1, dec_w2, lwt, ed);
    k_concat<<<(MTOK*CATP+255)/256, 256, 0, stream>>>(x, mask, cat);
    k_gemm<64,64,64, 1,0,1,0,0><<<g512,256,0,stream>>>(cat, CATP, enc1T, CATP, enc_b1, nullptr, nullptr, 0, enc_a1, 0, nullptr, hn, DMODEL, nullptr, MTOK, DMODEL, CATP);
    k_gemm<64,64,128,1,0,1,1,0><<<g512,256,0,stream>>>(hn, DMODEL, enc2T, DMODEL, enc_b2, nullptr, nullptr, 0, enc_a2, 0, nullptr, h, DMODEL, nullptr, MTOK, DMODEL, DMODEL);
    k_relemb<<<EROWS, 64, 0, stream>>>(rel_w1, rel_b1, rel_a, rel_w2, rel_b2, Ebf);

    for (int l = 0; l < NL; ++l) {
        size_t oB  = (size_t)l*DMODEL;
        size_t oBF1= (size_t)l*DFF;
        bf16* Lw = lwt + (size_t)l*LWT_ELEMS;

        k_layernorm<<<MTOK, 256, 0, stream>>>(h, ln_g, ln_b, hn);
        // fused QKV: N=1536; q|k -> qkb (pitch 1024), v -> VTb transposed
        k_gemm<64,128,64,0,0,3,0,1><<<gQKV,256,0,stream>>>(hn, DMODEL, Lw, DMODEL, bq, bk, bv, oB, nullptr, 0, nullptr, qkb, QKP, VTb, MTOK, 1536, DMODEL);
        k_attn<<<BB*NH*(TT/128), 512, 0, stream>>>(qkb, qkb + 512, VTb, Ebf, hn, QKP);
        k_gemm<64,64,128,0,1,1,1,0><<<g512,256,0,stream>>>(hn, DMODEL, Lw + 786432, DMODEL, bo, nullptr, nullptr, oB, nullptr, 0, h, h, DMODEL, nullptr, MTOK, DMODEL, DMODEL);
        k_layernorm<<<MTOK, 256, 0, stream>>>(h, ln_g, ln_b, hn);
        // fused FFN: f1 full N=2048 -> mid; f2 full K=2048 -> h (+resid)
        k_gemm<64,128,64,1,0,1,0,0><<<gF1,256,0,stream>>>(hn, DMODEL, Lw + 1048576, DMODEL, fb1, nullptr, nullptr, oBF1, fa, (size_t)l, nullptr, mid, DFF, nullptr, MTOK, DFF, DMODEL);
        if (l == NL-1)   // dual-output: h fp32 + hb bf16 (replaces k_cast)
            k_gemm<64,64,128,0,1,1,2,0><<<g512,256,0,stream>>>(mid, DFF, Lw + 2097152, DFF, fb2, nullptr, nullptr, oB, nullptr, 0, h, h, DMODEL, hb, MTOK, DMODEL, DFF);
        else
            k_gemm<64,64,128,0,1,1,1,0><<<g512,256,0,stream>>>(mid, DFF, Lw + 2097152, DFF, fb2, nullptr, nullptr, oB, nullptr, 0, h, h, DMODEL, nullptr, MTOK, DMODEL, DFF);
    }

    // decoder (k_cast and k_out fused into GEMM epilogues)
    k_gemm<64,64,128,1,0,1,0,0><<<g512,256,0,stream>>>(hb, DMODEL, dec1T, DMODEL, dec_b1, nullptr, nullptr, 0, dec_a, 0, nullptr, hn, DMODEL, nullptr, MTOK, DMODEL, DMODEL);
    {
        dim3 g2(2, 64);   // N=73: BN=64 -> 2 col tiles
        k_gemm<64,64,128,0,0,1,3,0><<<g2,256,0,stream>>>(hn, DMODEL, dec2T, DMODEL, dec_b2, nullptr, nullptr, 0, nullptr, 0, nullptr, d_out, DOF, nullptr, MTOK, DOF+4, DMODEL);
    }
}